// Round 9
// baseline (204.273 us; speedup 1.0000x reference)
//
#include <hip/hip_runtime.h>

#define S_LEN 2048
#define D_DIM 1024
#define NH    16
#define DHEAD 64

typedef float f32x4 __attribute__((ext_vector_type(4)));
typedef __bf16 bf16x8 __attribute__((ext_vector_type(8)));
typedef unsigned short u16;
typedef unsigned int u32;
typedef unsigned short u16x8 __attribute__((ext_vector_type(8)));
typedef unsigned short u16x4 __attribute__((ext_vector_type(4)));

__device__ __forceinline__ u16 f2bf(float f) {
    union { float f; unsigned u; } c; c.f = f;
    unsigned u = c.u + 0x7fffu + ((c.u >> 16) & 1u);
    return (u16)(u >> 16);
}

#if __has_builtin(__builtin_amdgcn_exp2f)
#define EXP2(x) __builtin_amdgcn_exp2f(x)
#else
#define EXP2(x) exp2f(x)
#endif

// 0.25*log2(e), 0.125*log2(e)
#define C_QK  0.36067376022224085f
#define C_SQ  0.18033688011112043f

#define MFMA16(a, b, c) __builtin_amdgcn_mfma_f32_16x16x32_bf16((a), (b), (c), 0, 0, 0)

// pack two f32 into bf16 pair (truncation; bias cancels in softmax normalize)
__device__ __forceinline__ u32 pack_bf(float lo, float hi) {
    union { float f; u32 u; } a, b; a.f = lo; b.f = hi;
    return (b.u & 0xFFFF0000u) | (a.u >> 16);
}

// ---------------------------------------------------------------------------
// Mpart[z][h*64+j][f] = 0.125 * sum_{e in z-chunk} Wq[e,h*64+j] * Wv[e,h*64+f]
// grid (8 z, 16 h). Both 128x64 head-slice panels staged in LDS (same cols!).
__global__ __launch_bounds__(256) void k_precomp_M(
    const float* __restrict__ Wq, const float* __restrict__ Wv, float* __restrict__ Mpart) {
    __shared__ float Qp[128][64];
    __shared__ float Vp[128][64];
    const int tid = threadIdx.x;
    const int z = blockIdx.x, h = blockIdx.y;
    {
        int r = tid >> 1, hf = tid & 1;
        const float* q = Wq + (size_t)(z * 128 + r) * D_DIM + h * DHEAD + hf * 32;
        const float* v = Wv + (size_t)(z * 128 + r) * D_DIM + h * DHEAD + hf * 32;
#pragma unroll
        for (int i = 0; i < 8; ++i) {
            *(f32x4*)&Qp[r][hf * 32 + i * 4] = *(const f32x4*)(q + i * 4);
            *(f32x4*)&Vp[r][hf * 32 + i * 4] = *(const f32x4*)(v + i * 4);
        }
    }
    __syncthreads();
    // per-thread 4x4 (j,f) tile; Qp read is a 16-lane broadcast, Vp 2-way
    const int j0 = (tid >> 4) * 4;      // 0..60
    const int f0 = (tid & 15) * 4;      // 0..60
    f32x4 acc[4];
    const f32x4 z4 = {0.f, 0.f, 0.f, 0.f};
#pragma unroll
    for (int i = 0; i < 4; ++i) acc[i] = z4;
    for (int e = 0; e < 128; ++e) {
        f32x4 qv = *(const f32x4*)&Qp[e][j0];
        f32x4 vv = *(const f32x4*)&Vp[e][f0];
#pragma unroll
        for (int jj = 0; jj < 4; ++jj)
            acc[jj] += qv[jj] * vv;
    }
    float* dst = Mpart + (size_t)z * (NH * 64 * 64) + ((size_t)(h * 64 + j0)) * 64 + f0;
#pragma unroll
    for (int jj = 0; jj < 4; ++jj) {
        f32x4 o = acc[jj] * 0.125f;
        *(f32x4*)(dst + jj * 64) = o;
    }
}

// ---------------------------------------------------------------------------
// W2[o, h*64+j] = sum_f (sum_z Mpart[z,h,j,f]) * Wout[o, h*64+f]   (bf16 out)
__global__ __launch_bounds__(256) void k_precomp_W2(
    const float* __restrict__ Mpart, const float* __restrict__ Wout, u16* __restrict__ W2) {
    __shared__ float Ms[64][65];
    __shared__ float Ws[64][65];
    const int tid = threadIdx.x;
    const int ob = blockIdx.x, h = blockIdx.y;
    {
        int rr = tid >> 2, seg = tid & 3;
        const size_t mo = ((size_t)(h * 64 + rr)) * 64 + seg * 16;
        const float* ws = Wout + (size_t)(ob * 64 + rr) * D_DIM + h * DHEAD + seg * 16;
#pragma unroll
        for (int e = 0; e < 16; ++e) {
            float s = 0.f;
#pragma unroll
            for (int k = 0; k < 8; ++k) s += Mpart[mo + e + (size_t)k * 65536];
            Ms[rr][seg * 16 + e] = s;
            Ws[rr][seg * 16 + e] = ws[e];
        }
    }
    __syncthreads();
    int j = tid & 63, o0 = (tid >> 6) * 16;
    for (int oo = o0; oo < o0 + 16; ++oo) {
        float acc = 0.f;
#pragma unroll
        for (int f = 0; f < 64; ++f) acc += Ms[j][f] * Ws[oo][f];
        W2[(size_t)(ob * 64 + oo) * D_DIM + h * DHEAD + j] = f2bf(acc);
    }
}

// ---------------------------------------------------------------------------
// Q projection, fp32 in (convert in staging), 128x128 tile, 512 threads,
// grid (32,8). Epilogue: Qbf + in-LDS transpose -> coalesced QT + sq05.
__global__ __launch_bounds__(512, 4) void k_qproj(
    const float* __restrict__ x, const float* __restrict__ Wq,
    const float* __restrict__ bq, const int* __restrict__ mask,
    u16* __restrict__ Qbf, u16* __restrict__ QT, float* __restrict__ sq05) {
    __shared__ __align__(16) char smem[38912];
    u16* Al = (u16*)smem;              // [128][72]
    u16* Bl = (u16*)(smem + 18432);    // [128][72]
    float* sqp = (float*)(smem + 36864); // [4][128]

    const int tid = threadIdx.x, lane = tid & 63, w = tid >> 6;
    const int wm = w & 1, wn = w >> 1;          // wn 0..3 (32-col quarters)
    const int col16 = lane & 15, quad = lane >> 4;
    const int bm = blockIdx.x, bn = blockIdx.y;

    f32x4 acc[4][2];
    const f32x4 z4 = {0.f, 0.f, 0.f, 0.f};
#pragma unroll
    for (int i = 0; i < 4; ++i)
#pragma unroll
        for (int j = 0; j < 2; ++j) acc[i][j] = z4;

    const int ar = tid >> 2, as = tid & 3;
    const float* pa = x + (size_t)(bm * 128 + ar) * D_DIM + as * 16;
    const float* pb = Wq + (size_t)(bn * 128 + ar) * D_DIM + as * 16;

    f32x4 fa[4], fb[4];
#pragma unroll
    for (int i = 0; i < 4; ++i) {
        fa[i] = *(const f32x4*)(pa + i * 4);
        fb[i] = *(const f32x4*)(pb + i * 4);
    }

    for (int k0 = 0; k0 < D_DIM; k0 += 64) {
        u16x8 wa[2], wb[2];
#pragma unroll
        for (int i = 0; i < 2; ++i)
#pragma unroll
            for (int e = 0; e < 4; ++e) {
                wa[i][e] = f2bf(fa[2 * i][e]); wa[i][e + 4] = f2bf(fa[2 * i + 1][e]);
                wb[i][e] = f2bf(fb[2 * i][e]); wb[i][e + 4] = f2bf(fb[2 * i + 1][e]);
            }
        __syncthreads();
#pragma unroll
        for (int i = 0; i < 2; ++i) *(u16x8*)&Al[ar * 72 + as * 16 + i * 8] = wa[i];
#pragma unroll
        for (int i = 0; i < 2; ++i) *(u16x8*)&Bl[ar * 72 + as * 16 + i * 8] = wb[i];
        __syncthreads();
        if (k0 + 64 < D_DIM) {
#pragma unroll
            for (int i = 0; i < 4; ++i) {
                fa[i] = *(const f32x4*)(pa + k0 + 64 + i * 4);
                fb[i] = *(const f32x4*)(pb + k0 + 64 + i * 4);
            }
        }
#pragma unroll
        for (int kh = 0; kh < 2; ++kh) {
            bf16x8 af[4];
#pragma unroll
            for (int mt = 0; mt < 4; ++mt)
                af[mt] = *(const bf16x8*)&Al[(wm * 64 + mt * 16 + col16) * 72 + kh * 32 + quad * 8];
#pragma unroll
            for (int nt = 0; nt < 2; ++nt) {
                bf16x8 bfr = *(const bf16x8*)&Bl[(wn * 32 + nt * 16 + col16) * 72 + kh * 32 + quad * 8];
#pragma unroll
                for (int mt = 0; mt < 4; ++mt)
                    acc[mt][nt] = MFMA16(af[mt], bfr, acc[mt][nt]);
            }
        }
    }

    // epilogue: bias, Qbf store, ||q||^2 partials, LDS transpose for QT
    const int hh = wn >> 1;                     // head half within tile
    f32x4 ssum[4];
#pragma unroll
    for (int mt = 0; mt < 4; ++mt) ssum[mt] = z4;

    u16 qv16[2][4][4];
#pragma unroll
    for (int nt = 0; nt < 2; ++nt) {
        int col = bn * 128 + wn * 32 + nt * 16 + col16;
        float bqv = bq[col];
#pragma unroll
        for (int mt = 0; mt < 4; ++mt) {
            int row0 = bm * 128 + wm * 64 + mt * 16 + quad * 4;
#pragma unroll
            for (int rr = 0; rr < 4; ++rr) {
                float qv = acc[mt][nt][rr] + bqv;
                ssum[mt][rr] += qv * qv;
                u16 bv = f2bf(qv);
                qv16[nt][mt][rr] = bv;
                Qbf[(size_t)(row0 + rr) * D_DIM + col] = bv;
            }
        }
    }
    // 16-lane reduce over this wave's 32 d
    float vred[4][4];
#pragma unroll
    for (int mt = 0; mt < 4; ++mt)
#pragma unroll
        for (int rr = 0; rr < 4; ++rr) {
            float v = ssum[mt][rr];
            v += __shfl_xor(v, 1); v += __shfl_xor(v, 2);
            v += __shfl_xor(v, 4); v += __shfl_xor(v, 8);
            vred[mt][rr] = v;
        }
    if (col16 == 0) {
#pragma unroll
        for (int mt = 0; mt < 4; ++mt)
#pragma unroll
            for (int rr = 0; rr < 4; ++rr)
                sqp[wn * 128 + wm * 64 + mt * 16 + quad * 4 + rr] = vred[mt][rr];
    }
    __syncthreads();   // MFMA frag reads done; Al/Bl reusable; sqp visible

    // transpose: Td[head][d][s_local], stride 130 u16
    u16* Td = (u16*)smem;
#pragma unroll
    for (int nt = 0; nt < 2; ++nt) {
        int dloc = (wn & 1) * 32 + nt * 16 + col16;
#pragma unroll
        for (int mt = 0; mt < 4; ++mt) {
            int sl = wm * 64 + mt * 16 + quad * 4;
#pragma unroll
            for (int rr = 0; rr < 4; ++rr)
                Td[(hh * 64 + dloc) * 130 + sl + rr] = qv16[nt][mt][rr];
        }
    }
    __syncthreads();

    const int bb = (bm * 128) >> 11, s0 = (bm * 128) & 2047;
    if (tid < 256) {
        int r = tid & 127, hh2 = tid >> 7;
        float v = sqp[(2 * hh2) * 128 + r] + sqp[(2 * hh2 + 1) * 128 + r];
        int sidx = s0 + r;
        float o = mask[bb * S_LEN + sidx] ? v * C_SQ : 1e30f;
        sq05[((size_t)(bb * NH + bn * 2 + hh2)) * S_LEN + sidx] = o;
    }
    {
        int dr = tid >> 2, ch = tid & 3;
        int hh3 = dr >> 6, d = dr & 63;
        u16* dst = QT + ((size_t)(bb * NH + bn * 2 + hh3) * DHEAD + d) * S_LEN + s0 + ch * 32;
        const u16* src = Td + (hh3 * 64 + d) * 130 + ch * 32;
#pragma unroll
        for (int i = 0; i < 4; ++i)
            *(u16x8*)(dst + i * 8) = *(const u16x8*)(src + i * 8);
    }
}

// ---------------------------------------------------------------------------
// Fused L2 attention, transpose-free, kt-split. XCD-swizzled: blocks of one
// (b,h) share blockIdx%8 -> same XCD L2 serves the K-stream re-reads.
__global__ __launch_bounds__(256, 2) void k_flash(
    const u16* __restrict__ Qbf, const u16* __restrict__ QT,
    const float* __restrict__ sq05, u16* __restrict__ attnO) {
    __shared__ __align__(16) char smem[34816];
    u16* Kt  = (u16*)smem;              // [128][64] u16, xor-swizzled cols
    u16* KtT = (u16*)(smem + 16384);    // [64][128] u16, xor-swizzled cols
    float* sql = (float*)(smem + 32768);// [128]

    const int tid = threadIdx.x, lane = tid & 63, w = tid >> 6;
    const int col16 = lane & 15, quad = lane >> 4;
    const int wq = w & 1, wk = w >> 1;
    const int bh = blockIdx.x & 31;      // (b,h) in low bits -> same XCD
    const int qt = blockIdx.x >> 5;
    const int h = bh & 15;
    const int b = bh >> 4;
    const u16* qbase = Qbf + (size_t)b * S_LEN * D_DIM + h * DHEAD;
    const u16* qtbase = QT + ((size_t)(b * NH + h)) * DHEAD * S_LEN;
    const float* sqb = sq05 + ((size_t)(b * NH + h)) * S_LEN;

    // loop-invariant Q^T B-fragments (global, once)
    bf16x8 qb[4][2];
#pragma unroll
    for (int nq = 0; nq < 4; ++nq)
#pragma unroll
        for (int k0 = 0; k0 < 2; ++k0)
            qb[nq][k0] = *(const bf16x8*)(qbase +
                (size_t)(qt * 128 + wq * 64 + nq * 16 + col16) * D_DIM + k0 * 32 + quad * 8);

    // Kt read offset closed form: krow(kt,kbh) = krow00 + kt*2048 + kbh*256
    const int r00 = wk * 64 + (col16 >> 2) * 8 + (col16 & 3);
    const int swzA = (col16 & 3) | (((col16 >> 2) & 1) << 2);
    const int krow00 = r00 * 64 + (quad ^ swzA) * 8;
    const int sq00 = wk * 64 + quad * 8;
    // KtT read offsets per dblk (kt handled by ^32)
    int vrow[4];
#pragma unroll
    for (int dblk = 0; dblk < 4; ++dblk) {
        int rT = dblk * 16 + col16;
        vrow[dblk] = rT * 128 + ((wk * 8 + quad) ^ (rT & 7)) * 8;
    }

    // staging assignments
    const int kr = tid >> 1, ks = tid & 1;
    const int td = tid >> 2, ts = tid & 3;
    const int kswz = (kr & 3) | (((kr >> 3) & 1) << 2);
    const int tswz = td & 7;
    const u16* ksrc = qbase + (size_t)kr * D_DIM + ks * 32;
    const u16* tsrc = qtbase + (size_t)td * S_LEN + ts * 32;

    u16x8 pk[4], pt[4];
    float sv = 0.f;
#pragma unroll
    for (int i = 0; i < 4; ++i) pk[i] = *(const u16x8*)(ksrc + i * 8);
#pragma unroll
    for (int i = 0; i < 4; ++i) pt[i] = *(const u16x8*)(tsrc + i * 8);
    if (tid < 128) sv = sqb[tid];

    f32x4 Oacc[4][4], lacc[4];
    const f32x4 z4 = {0.f, 0.f, 0.f, 0.f};
#pragma unroll
    for (int n = 0; n < 4; ++n) {
        lacc[n] = z4;
#pragma unroll
        for (int d = 0; d < 4; ++d) Oacc[d][n] = z4;
    }
    bf16x8 ones;
    {
        union { u16x8 u; bf16x8 b; } cv;
#pragma unroll
        for (int e = 0; e < 8; ++e) cv.u[e] = 0x3F80;
        ones = cv.b;
    }

    for (int j = 0; j < S_LEN / 128; ++j) {
        __syncthreads();
#pragma unroll
        for (int i = 0; i < 4; ++i)
            *(u16x8*)(Kt + kr * 64 + ((ks * 4 + i) ^ kswz) * 8) = pk[i];
#pragma unroll
        for (int i = 0; i < 4; ++i)
            *(u16x8*)(KtT + td * 128 + ((ts * 4 + i) ^ tswz) * 8) = pt[i];
        if (tid < 128) sql[tid] = sv;
        __syncthreads();

        int jn = (j + 1) & 15;
        {
            const u16* kn = ksrc + (size_t)jn * 128 * D_DIM;
            const u16* tn = tsrc + (size_t)jn * 128;
#pragma unroll
            for (int i = 0; i < 4; ++i) pk[i] = *(const u16x8*)(kn + i * 8);
#pragma unroll
            for (int i = 0; i < 4; ++i) pt[i] = *(const u16x8*)(tn + i * 8);
            if (tid < 128) sv = sqb[jn * 128 + tid];
        }

        // two key-half rounds: S^T (32 keys x 64 q) -> exp/pack -> PV
        for (int kt = 0; kt < 2; ++kt) {
            f32x4 sacc[2][4];
#pragma unroll
            for (int kbh = 0; kbh < 2; ++kbh)
#pragma unroll
                for (int nq = 0; nq < 4; ++nq) sacc[kbh][nq] = z4;
#pragma unroll
            for (int kbh = 0; kbh < 2; ++kbh) {
                int kro = krow00 + kt * 2048 + kbh * 256;
                bf16x8 a0 = *(const bf16x8*)(Kt + kro);
                bf16x8 a1 = *(const bf16x8*)(Kt + (kro ^ 32));
#pragma unroll
                for (int nq = 0; nq < 4; ++nq) {
                    sacc[kbh][nq] = MFMA16(a0, qb[nq][0], sacc[kbh][nq]);
                    sacc[kbh][nq] = MFMA16(a1, qb[nq][1], sacc[kbh][nq]);
                }
            }

            // hoist V-fragment LDS reads: latency hides under the exp chain
            bf16x8 va[4];
#pragma unroll
            for (int dblk = 0; dblk < 4; ++dblk)
                va[dblk] = *(const bf16x8*)(KtT + (vrow[dblk] ^ (kt * 32)));

            u32 pf[4][4];
#pragma unroll
            for (int kbh = 0; kbh < 2; ++kbh) {
                f32x4 sqv = *(const f32x4*)(sql + sq00 + kt * 32 + kbh * 4);
#pragma unroll
                for (int nq = 0; nq < 4; ++nq) {
                    float p0 = EXP2(fmaf(sacc[kbh][nq][0], C_QK, -sqv[0]));
                    float p1 = EXP2(fmaf(sacc[kbh][nq][1], C_QK, -sqv[1]));
                    float p2 = EXP2(fmaf(sacc[kbh][nq][2], C_QK, -sqv[2]));
                    float p3 = EXP2(fmaf(sacc[kbh][nq][3], C_QK, -sqv[3]));
                    pf[nq][kbh * 2]     = pack_bf(p0, p1);
                    pf[nq][kbh * 2 + 1] = pack_bf(p2, p3);
                }
            }

#pragma unroll
            for (int nq = 0; nq < 4; ++nq) {
                union { u32 u[4]; bf16x8 b; } pb;
#pragma unroll
                for (int i = 0; i < 4; ++i) pb.u[i] = pf[nq][i];
                lacc[nq] = MFMA16(ones, pb.b, lacc[nq]);   // key-sums, rows replicated
#pragma unroll
                for (int dblk = 0; dblk < 4; ++dblk)
                    Oacc[dblk][nq] = MFMA16(va[dblk], pb.b, Oacc[dblk][nq]);
            }
        }
    }

    // cross-wave (key-half) combine + epilogue
    __syncthreads();
    float* Obuf = (float*)smem;                 // [2][16][64] f32x4 = 32 KB
    float* lred = (float*)(smem + 32768);       // [2][4][64]
    if (wk == 1) {
#pragma unroll
        for (int dblk = 0; dblk < 4; ++dblk)
#pragma unroll
            for (int nq = 0; nq < 4; ++nq)
                *(f32x4*)(Obuf + ((wq * 16 + dblk * 4 + nq) * 64 + lane) * 4) = Oacc[dblk][nq];
#pragma unroll
        for (int nq = 0; nq < 4; ++nq)
            lred[(wq * 4 + nq) * 64 + lane] = lacc[nq][0];
    }
    __syncthreads();
    if (wk == 0) {
        float rinv[4];
#pragma unroll
        for (int nq = 0; nq < 4; ++nq)
            rinv[nq] = 1.f / (lacc[nq][0] + lred[(wq * 4 + nq) * 64 + lane]);
        u16* obase = attnO + (size_t)b * S_LEN * D_DIM + h * DHEAD;
#pragma unroll
        for (int dblk = 0; dblk < 4; ++dblk)
#pragma unroll
            for (int nq = 0; nq < 4; ++nq) {
                f32x4 o = Oacc[dblk][nq] + *(const f32x4*)(Obuf + ((wq * 16 + dblk * 4 + nq) * 64 + lane) * 4);
                int q = qt * 128 + wq * 64 + nq * 16 + col16;
                u16x4 pkk;
#pragma unroll
                for (int rr = 0; rr < 4; ++rr) pkk[rr] = f2bf(o[rr] * rinv[nq]);
                *(u16x4*)(obase + (size_t)q * D_DIM + dblk * 16 + quad * 4) = pkk;
            }
    }
}

// ---------------------------------------------------------------------------
// Output GEMM, 128x128 tile, 512 threads, grid (32,8):
// out[s,o] = x[s,o] + bout[o] + attnO·W2^T
__global__ __launch_bounds__(512, 4) void k_oproj(
    const u16* __restrict__ attnO, const u16* __restrict__ W2,
    const float* __restrict__ x, const float* __restrict__ bout, float* __restrict__ out) {
    __shared__ __align__(16) char smem[36864];
    u16* Al = (u16*)smem;              // [128][72]
    u16* Bl = (u16*)(smem + 18432);    // [128][72]
    const int tid = threadIdx.x, lane = tid & 63, w = tid >> 6;
    const int wm = w & 1, wn = w >> 1;
    const int col16 = lane & 15, quad = lane >> 4;
    const int bm = blockIdx.x, bn = blockIdx.y;

    f32x4 acc[4][2];
    const f32x4 z4 = {0.f, 0.f, 0.f, 0.f};
#pragma unroll
    for (int i = 0; i < 4; ++i)
#pragma unroll
        for (int j = 0; j < 2; ++j) acc[i][j] = z4;

    const int ar = tid >> 2, as = tid & 3;
    const u16* pa = attnO + (size_t)(bm * 128 + ar) * D_DIM + as * 16;
    const u16* pb = W2 + (size_t)(bn * 128 + ar) * D_DIM + as * 16;

    u16x8 ra[2], rb[2];
#pragma unroll
    for (int i = 0; i < 2; ++i) ra[i] = *(const u16x8*)(pa + i * 8);
#pragma unroll
    for (int i = 0; i < 2; ++i) rb[i] = *(const u16x8*)(pb + i * 8);

    for (int k0 = 0; k0 < D_DIM; k0 += 64) {
        __syncthreads();
#pragma unroll
        for (int i = 0; i < 2; ++i) *(u16x8*)&Al[ar * 72 + as * 16 + i * 8] = ra[i];
#pragma unroll
        for (int i = 0; i < 2; ++i) *(u16x8*)&Bl[ar * 72 + as * 16 + i * 8] = rb[i];
        __syncthreads();
        if (k0 + 64 < D_DIM) {
#pragma unroll
            for (int i = 0; i < 2; ++i) ra[i] = *(const u16x8*)(pa + k0 + 64 + i * 8);
#pragma unroll
            for (int i = 0; i < 2; ++i) rb[i] = *(const u16x8*)(pb + k0 + 64 + i * 8);
        }
#pragma unroll
        for (int kh = 0; kh < 2; ++kh) {
            bf16x8 af[4];
#pragma unroll
            for (int mt = 0; mt < 4; ++mt)
                af[mt] = *(const bf16x8*)&Al[(wm * 64 + mt * 16 + col16) * 72 + kh * 32 + quad * 8];
#pragma unroll
            for (int nt = 0; nt < 2; ++nt) {
                bf16x8 bfr = *(const bf16x8*)&Bl[(wn * 32 + nt * 16 + col16) * 72 + kh * 32 + quad * 8];
#pragma unroll
                for (int mt = 0; mt < 4; ++mt)
                    acc[mt][nt] = MFMA16(af[mt], bfr, acc[mt][nt]);
            }
        }
    }
#pragma unroll
    for (int nt = 0; nt < 2; ++nt) {
        int col = bn * 128 + wn * 32 + nt * 16 + col16;
        float bv = bout[col];
#pragma unroll
        for (int mt = 0; mt < 4; ++mt) {
            int row0 = bm * 128 + wm * 64 + mt * 16 + quad * 4;
#pragma unroll
            for (int rr = 0; rr < 4; ++rr) {
                size_t idx = (size_t)(row0 + rr) * D_DIM + col;
                out[idx] = acc[mt][nt][rr] + x[idx] + bv;
            }
        }
    }
}

// ---------------------------------------------------------------------------
extern "C" void kernel_launch(void* const* d_in, const int* in_sizes, int n_in,
                              void* d_out, int out_size, void* d_ws, size_t ws_size,
                              hipStream_t stream) {
    const float* x    = (const float*)d_in[0];
    const float* Wq   = (const float*)d_in[1];
    const float* bq   = (const float*)d_in[2];
    const float* Wv   = (const float*)d_in[3];
    const float* Wout = (const float*)d_in[4];
    const float* bout = (const float*)d_in[5];
    const int*   mask = (const int*)d_in[6];
    float* out = (float*)d_out;

    char* ws = (char*)d_ws;
    u16*   Qbf   = (u16*)(ws);                         // 8 MB
    u16*   QT    = (u16*)(ws + (8u << 20));            // 8 MB
    u16*   attnO = (u16*)(ws + (16u << 20));           // 8 MB
    u16*   W2    = (u16*)(ws + (24u << 20));           // 2 MB
    float* Mpart = (float*)(ws + (26u << 20));         // 2 MB (8 partials)
    float* sq05  = (float*)(ws + (28u << 20));         // 256 KB

    k_precomp_M<<<dim3(8, 16), dim3(256), 0, stream>>>(Wq, Wv, Mpart);
    k_precomp_W2<<<dim3(16, 16), dim3(256), 0, stream>>>(Mpart, Wout, W2);
    k_qproj<<<dim3(32, 8), dim3(512), 0, stream>>>(x, Wq, bq, mask, Qbf, QT, sq05);
    k_flash<<<dim3(512), dim3(256), 0, stream>>>(Qbf, QT, sq05, attnO);
    k_oproj<<<dim3(32, 8), dim3(512), 0, stream>>>(attnO, W2, x, bout, out);
}

// Round 10
// 184.625 us; speedup vs baseline: 1.1064x; 1.1064x over previous
//
#include <hip/hip_runtime.h>

#define S_LEN 2048
#define D_DIM 1024
#define NH    16
#define DHEAD 64

typedef float f32x4 __attribute__((ext_vector_type(4)));
typedef __bf16 bf16x8 __attribute__((ext_vector_type(8)));
typedef unsigned short u16;
typedef unsigned int u32;
typedef unsigned short u16x8 __attribute__((ext_vector_type(8)));
typedef unsigned short u16x4 __attribute__((ext_vector_type(4)));

__device__ __forceinline__ u16 f2bf(float f) {
    union { float f; unsigned u; } c; c.f = f;
    unsigned u = c.u + 0x7fffu + ((c.u >> 16) & 1u);
    return (u16)(u >> 16);
}

#if __has_builtin(__builtin_amdgcn_exp2f)
#define EXP2(x) __builtin_amdgcn_exp2f(x)
#else
#define EXP2(x) exp2f(x)
#endif

// 0.25*log2(e), 0.125*log2(e)
#define C_QK  0.36067376022224085f
#define C_SQ  0.18033688011112043f

#define MFMA16(a, b, c) __builtin_amdgcn_mfma_f32_16x16x32_bf16((a), (b), (c), 0, 0, 0)

// pack two f32 into bf16 pair (truncation; bias cancels in softmax normalize)
__device__ __forceinline__ u32 pack_bf(float lo, float hi) {
    union { float f; u32 u; } a, b; a.f = lo; b.f = hi;
    return (b.u & 0xFFFF0000u) | (a.u >> 16);
}

// ---------------------------------------------------------------------------
// MEGA-1: blocks 0..255 = Q projection (128x128, bn = 2-head group)
//         blocks 256..383 = Mpart[z][h*64+j][f] partial Wq^T.Wv (8 z-chunks)
__global__ __launch_bounds__(512, 4) void k_mega1(
    const float* __restrict__ x, const float* __restrict__ Wq,
    const float* __restrict__ Wv, const float* __restrict__ bq,
    const int* __restrict__ mask, u16* __restrict__ Qbf, u16* __restrict__ QT,
    float* __restrict__ sq05, float* __restrict__ Mpart) {
    __shared__ __align__(16) char smem[38912];
    const int tid = threadIdx.x;

    if (blockIdx.x >= 256) {
        // ---------------- precomp_M path ----------------
        const int id = blockIdx.x - 256;
        const int z = id & 7, h = id >> 3;
        float* Qp = (float*)smem;              // [64][64]
        float* Vp = (float*)(smem + 16384);    // [64][64]
        const int r = tid >> 3, seg = tid & 7;
        const int j0 = (tid >> 4) * 2;         // 2 j's
        const int f0 = (tid & 15) * 4;         // 4 f's
        f32x4 acc0 = {0.f, 0.f, 0.f, 0.f}, acc1 = acc0;
        for (int c = 0; c < 2; ++c) {
            const int e0 = z * 128 + c * 64;
            __syncthreads();
            const float* q = Wq + (size_t)(e0 + r) * D_DIM + h * DHEAD + seg * 8;
            const float* v = Wv + (size_t)(e0 + r) * D_DIM + h * DHEAD + seg * 8;
            *(f32x4*)&Qp[r * 64 + seg * 8]     = *(const f32x4*)q;
            *(f32x4*)&Qp[r * 64 + seg * 8 + 4] = *(const f32x4*)(q + 4);
            *(f32x4*)&Vp[r * 64 + seg * 8]     = *(const f32x4*)v;
            *(f32x4*)&Vp[r * 64 + seg * 8 + 4] = *(const f32x4*)(v + 4);
            __syncthreads();
#pragma unroll 8
            for (int e = 0; e < 64; ++e) {
                float q0 = Qp[e * 64 + j0], q1 = Qp[e * 64 + j0 + 1];
                f32x4 vv = *(const f32x4*)&Vp[e * 64 + f0];
                acc0 += q0 * vv;
                acc1 += q1 * vv;
            }
        }
        float* dst = Mpart + (size_t)z * 65536 + ((size_t)(h * 64 + j0)) * 64 + f0;
        *(f32x4*)dst        = acc0 * 0.125f;
        *(f32x4*)(dst + 64) = acc1 * 0.125f;
        return;
    }

    // ---------------- qproj path ----------------
    u16* Al = (u16*)smem;              // [128][72]
    u16* Bl = (u16*)(smem + 18432);    // [128][72]
    float* sqp = (float*)(smem + 36864); // [4][128]

    const int lane = tid & 63, w = tid >> 6;
    const int wm = w & 1, wn = w >> 1;          // wn 0..3 (32-col quarters)
    const int col16 = lane & 15, quad = lane >> 4;
    const int bm = blockIdx.x & 31, bn = blockIdx.x >> 5;

    f32x4 acc[4][2];
    const f32x4 z4 = {0.f, 0.f, 0.f, 0.f};
#pragma unroll
    for (int i = 0; i < 4; ++i)
#pragma unroll
        for (int j = 0; j < 2; ++j) acc[i][j] = z4;

    const int ar = tid >> 2, as = tid & 3;
    const float* pa = x + (size_t)(bm * 128 + ar) * D_DIM + as * 16;
    const float* pb = Wq + (size_t)(bn * 128 + ar) * D_DIM + as * 16;

    f32x4 fa[4], fb[4];
#pragma unroll
    for (int i = 0; i < 4; ++i) {
        fa[i] = *(const f32x4*)(pa + i * 4);
        fb[i] = *(const f32x4*)(pb + i * 4);
    }

    for (int k0 = 0; k0 < D_DIM; k0 += 64) {
        u16x8 wa[2], wb[2];
#pragma unroll
        for (int i = 0; i < 2; ++i)
#pragma unroll
            for (int e = 0; e < 4; ++e) {
                wa[i][e] = f2bf(fa[2 * i][e]); wa[i][e + 4] = f2bf(fa[2 * i + 1][e]);
                wb[i][e] = f2bf(fb[2 * i][e]); wb[i][e + 4] = f2bf(fb[2 * i + 1][e]);
            }
        __syncthreads();
#pragma unroll
        for (int i = 0; i < 2; ++i) *(u16x8*)&Al[ar * 72 + as * 16 + i * 8] = wa[i];
#pragma unroll
        for (int i = 0; i < 2; ++i) *(u16x8*)&Bl[ar * 72 + as * 16 + i * 8] = wb[i];
        __syncthreads();
        if (k0 + 64 < D_DIM) {
#pragma unroll
            for (int i = 0; i < 4; ++i) {
                fa[i] = *(const f32x4*)(pa + k0 + 64 + i * 4);
                fb[i] = *(const f32x4*)(pb + k0 + 64 + i * 4);
            }
        }
#pragma unroll
        for (int kh = 0; kh < 2; ++kh) {
            bf16x8 af[4];
#pragma unroll
            for (int mt = 0; mt < 4; ++mt)
                af[mt] = *(const bf16x8*)&Al[(wm * 64 + mt * 16 + col16) * 72 + kh * 32 + quad * 8];
#pragma unroll
            for (int nt = 0; nt < 2; ++nt) {
                bf16x8 bfr = *(const bf16x8*)&Bl[(wn * 32 + nt * 16 + col16) * 72 + kh * 32 + quad * 8];
#pragma unroll
                for (int mt = 0; mt < 4; ++mt)
                    acc[mt][nt] = MFMA16(af[mt], bfr, acc[mt][nt]);
            }
        }
    }

    // epilogue: bias, Qbf store, ||q||^2 partials, LDS transpose for QT
    const int hh = wn >> 1;                     // head half within tile
    f32x4 ssum[4];
#pragma unroll
    for (int mt = 0; mt < 4; ++mt) ssum[mt] = z4;

    u16 qv16[2][4][4];
#pragma unroll
    for (int nt = 0; nt < 2; ++nt) {
        int col = bn * 128 + wn * 32 + nt * 16 + col16;
        float bqv = bq[col];
#pragma unroll
        for (int mt = 0; mt < 4; ++mt) {
            int row0 = bm * 128 + wm * 64 + mt * 16 + quad * 4;
#pragma unroll
            for (int rr = 0; rr < 4; ++rr) {
                float qv = acc[mt][nt][rr] + bqv;
                ssum[mt][rr] += qv * qv;
                u16 bv = f2bf(qv);
                qv16[nt][mt][rr] = bv;
                Qbf[(size_t)(row0 + rr) * D_DIM + col] = bv;
            }
        }
    }
    float vred[4][4];
#pragma unroll
    for (int mt = 0; mt < 4; ++mt)
#pragma unroll
        for (int rr = 0; rr < 4; ++rr) {
            float v = ssum[mt][rr];
            v += __shfl_xor(v, 1); v += __shfl_xor(v, 2);
            v += __shfl_xor(v, 4); v += __shfl_xor(v, 8);
            vred[mt][rr] = v;
        }
    if (col16 == 0) {
#pragma unroll
        for (int mt = 0; mt < 4; ++mt)
#pragma unroll
            for (int rr = 0; rr < 4; ++rr)
                sqp[wn * 128 + wm * 64 + mt * 16 + quad * 4 + rr] = vred[mt][rr];
    }
    __syncthreads();   // MFMA frag reads done; Al/Bl reusable; sqp visible

    // transpose: Td[head][d][s_local], stride 130 u16
    u16* Td = (u16*)smem;
#pragma unroll
    for (int nt = 0; nt < 2; ++nt) {
        int dloc = (wn & 1) * 32 + nt * 16 + col16;
#pragma unroll
        for (int mt = 0; mt < 4; ++mt) {
            int sl = wm * 64 + mt * 16 + quad * 4;
#pragma unroll
            for (int rr = 0; rr < 4; ++rr)
                Td[(hh * 64 + dloc) * 130 + sl + rr] = qv16[nt][mt][rr];
        }
    }
    __syncthreads();

    const int bb = (bm * 128) >> 11, s0 = (bm * 128) & 2047;
    if (tid < 256) {
        int r = tid & 127, hh2 = tid >> 7;
        float v = sqp[(2 * hh2) * 128 + r] + sqp[(2 * hh2 + 1) * 128 + r];
        int sidx = s0 + r;
        float o = mask[bb * S_LEN + sidx] ? v * C_SQ : 1e30f;
        sq05[((size_t)(bb * NH + bn * 2 + hh2)) * S_LEN + sidx] = o;
    }
    {
        int dr = tid >> 2, ch = tid & 3;
        int hh3 = dr >> 6, d = dr & 63;
        u16* dst = QT + ((size_t)(bb * NH + bn * 2 + hh3) * DHEAD + d) * S_LEN + s0 + ch * 32;
        const u16* src = Td + (hh3 * 64 + d) * 130 + ch * 32;
#pragma unroll
        for (int i = 0; i < 4; ++i)
            *(u16x8*)(dst + i * 8) = *(const u16x8*)(src + i * 8);
    }
}

// ---------------------------------------------------------------------------
// MEGA-2: blocks 0..511 = fused L2 attention (XCD-swizzled, unchanged)
//         blocks 512..767 = W2[o,c] = (sum_z Mpart) · Wout fold
__global__ __launch_bounds__(256, 2) void k_mega2(
    const u16* __restrict__ Qbf, const u16* __restrict__ QT,
    const float* __restrict__ sq05, u16* __restrict__ attnO,
    const float* __restrict__ Mpart, const float* __restrict__ Wout,
    u16* __restrict__ W2) {
    __shared__ __align__(16) char smem[34816];
    const int tid = threadIdx.x;

    if (blockIdx.x >= 512) {
        // ---------------- precomp_W2 path ----------------
        const int id = blockIdx.x - 512;
        const int ob = id & 15, h = id >> 4;
        float* Ms = (float*)smem;              // [64][65]
        float* Ws = (float*)(smem + 16640);    // [64][65]
        {
            int rr = tid >> 2, seg = tid & 3;
            const size_t mo = ((size_t)(h * 64 + rr)) * 64 + seg * 16;
            const float* ws = Wout + (size_t)(ob * 64 + rr) * D_DIM + h * DHEAD + seg * 16;
#pragma unroll
            for (int e = 0; e < 16; ++e) {
                float s = 0.f;
#pragma unroll
                for (int k = 0; k < 8; ++k) s += Mpart[mo + e + (size_t)k * 65536];
                Ms[rr * 65 + seg * 16 + e] = s;
                Ws[rr * 65 + seg * 16 + e] = ws[e];
            }
        }
        __syncthreads();
        int j = tid & 63, o0 = (tid >> 6) * 16;
        for (int oo = o0; oo < o0 + 16; ++oo) {
            float acc = 0.f;
#pragma unroll
            for (int f = 0; f < 64; ++f) acc += Ms[j * 65 + f] * Ws[oo * 65 + f];
            W2[(size_t)(ob * 64 + oo) * D_DIM + h * DHEAD + j] = f2bf(acc);
        }
        return;
    }

    // ---------------- flash path ----------------
    u16* Kt  = (u16*)smem;              // [128][64] u16, xor-swizzled cols
    u16* KtT = (u16*)(smem + 16384);    // [64][128] u16, xor-swizzled cols
    float* sql = (float*)(smem + 32768);// [128]

    const int lane = tid & 63, w = tid >> 6;
    const int col16 = lane & 15, quad = lane >> 4;
    const int wq = w & 1, wk = w >> 1;
    const int bh = blockIdx.x & 31;      // (b,h) in low bits -> same XCD
    const int qt = blockIdx.x >> 5;
    const int h = bh & 15;
    const int b = bh >> 4;
    const u16* qbase = Qbf + (size_t)b * S_LEN * D_DIM + h * DHEAD;
    const u16* qtbase = QT + ((size_t)(b * NH + h)) * DHEAD * S_LEN;
    const float* sqb = sq05 + ((size_t)(b * NH + h)) * S_LEN;

    // loop-invariant Q^T B-fragments (global, once)
    bf16x8 qb[4][2];
#pragma unroll
    for (int nq = 0; nq < 4; ++nq)
#pragma unroll
        for (int k0 = 0; k0 < 2; ++k0)
            qb[nq][k0] = *(const bf16x8*)(qbase +
                (size_t)(qt * 128 + wq * 64 + nq * 16 + col16) * D_DIM + k0 * 32 + quad * 8);

    // Kt read offset closed form: krow(kt,kbh) = krow00 + kt*2048 + kbh*256
    const int r00 = wk * 64 + (col16 >> 2) * 8 + (col16 & 3);
    const int swzA = (col16 & 3) | (((col16 >> 2) & 1) << 2);
    const int krow00 = r00 * 64 + (quad ^ swzA) * 8;
    const int sq00 = wk * 64 + quad * 8;
    int vrow[4];
#pragma unroll
    for (int dblk = 0; dblk < 4; ++dblk) {
        int rT = dblk * 16 + col16;
        vrow[dblk] = rT * 128 + ((wk * 8 + quad) ^ (rT & 7)) * 8;
    }

    // staging assignments
    const int kr = tid >> 1, ks = tid & 1;
    const int td = tid >> 2, ts = tid & 3;
    const int kswz = (kr & 3) | (((kr >> 3) & 1) << 2);
    const int tswz = td & 7;
    const u16* ksrc = qbase + (size_t)kr * D_DIM + ks * 32;
    const u16* tsrc = qtbase + (size_t)td * S_LEN + ts * 32;

    u16x8 pk[4], pt[4];
    float sv = 0.f;
#pragma unroll
    for (int i = 0; i < 4; ++i) pk[i] = *(const u16x8*)(ksrc + i * 8);
#pragma unroll
    for (int i = 0; i < 4; ++i) pt[i] = *(const u16x8*)(tsrc + i * 8);
    if (tid < 128) sv = sqb[tid];

    f32x4 Oacc[4][4], lacc[4];
    const f32x4 z4 = {0.f, 0.f, 0.f, 0.f};
#pragma unroll
    for (int n = 0; n < 4; ++n) {
        lacc[n] = z4;
#pragma unroll
        for (int d = 0; d < 4; ++d) Oacc[d][n] = z4;
    }
    bf16x8 ones;
    {
        union { u16x8 u; bf16x8 b; } cv;
#pragma unroll
        for (int e = 0; e < 8; ++e) cv.u[e] = 0x3F80;
        ones = cv.b;
    }

    for (int j = 0; j < S_LEN / 128; ++j) {
        __syncthreads();
#pragma unroll
        for (int i = 0; i < 4; ++i)
            *(u16x8*)(Kt + kr * 64 + ((ks * 4 + i) ^ kswz) * 8) = pk[i];
#pragma unroll
        for (int i = 0; i < 4; ++i)
            *(u16x8*)(KtT + td * 128 + ((ts * 4 + i) ^ tswz) * 8) = pt[i];
        if (tid < 128) sql[tid] = sv;
        __syncthreads();

        int jn = (j + 1) & 15;
        {
            const u16* kn = ksrc + (size_t)jn * 128 * D_DIM;
            const u16* tn = tsrc + (size_t)jn * 128;
#pragma unroll
            for (int i = 0; i < 4; ++i) pk[i] = *(const u16x8*)(kn + i * 8);
#pragma unroll
            for (int i = 0; i < 4; ++i) pt[i] = *(const u16x8*)(tn + i * 8);
            if (tid < 128) sv = sqb[jn * 128 + tid];
        }

        // two key-half rounds: S^T (32 keys x 64 q) -> exp/pack -> PV
        for (int kt = 0; kt < 2; ++kt) {
            f32x4 sacc[2][4];
#pragma unroll
            for (int kbh = 0; kbh < 2; ++kbh)
#pragma unroll
                for (int nq = 0; nq < 4; ++nq) sacc[kbh][nq] = z4;
#pragma unroll
            for (int kbh = 0; kbh < 2; ++kbh) {
                int kro = krow00 + kt * 2048 + kbh * 256;
                bf16x8 a0 = *(const bf16x8*)(Kt + kro);
                bf16x8 a1 = *(const bf16x8*)(Kt + (kro ^ 32));
#pragma unroll
                for (int nq = 0; nq < 4; ++nq) {
                    sacc[kbh][nq] = MFMA16(a0, qb[nq][0], sacc[kbh][nq]);
                    sacc[kbh][nq] = MFMA16(a1, qb[nq][1], sacc[kbh][nq]);
                }
            }

            // hoist V-fragment LDS reads: latency hides under the exp chain
            bf16x8 va[4];
#pragma unroll
            for (int dblk = 0; dblk < 4; ++dblk)
                va[dblk] = *(const bf16x8*)(KtT + (vrow[dblk] ^ (kt * 32)));

            u32 pf[4][4];
#pragma unroll
            for (int kbh = 0; kbh < 2; ++kbh) {
                f32x4 sqv = *(const f32x4*)(sql + sq00 + kt * 32 + kbh * 4);
#pragma unroll
                for (int nq = 0; nq < 4; ++nq) {
                    float p0 = EXP2(fmaf(sacc[kbh][nq][0], C_QK, -sqv[0]));
                    float p1 = EXP2(fmaf(sacc[kbh][nq][1], C_QK, -sqv[1]));
                    float p2 = EXP2(fmaf(sacc[kbh][nq][2], C_QK, -sqv[2]));
                    float p3 = EXP2(fmaf(sacc[kbh][nq][3], C_QK, -sqv[3]));
                    pf[nq][kbh * 2]     = pack_bf(p0, p1);
                    pf[nq][kbh * 2 + 1] = pack_bf(p2, p3);
                }
            }

#pragma unroll
            for (int nq = 0; nq < 4; ++nq) {
                union { u32 u[4]; bf16x8 b; } pb;
#pragma unroll
                for (int i = 0; i < 4; ++i) pb.u[i] = pf[nq][i];
                lacc[nq] = MFMA16(ones, pb.b, lacc[nq]);   // key-sums, rows replicated
#pragma unroll
                for (int dblk = 0; dblk < 4; ++dblk)
                    Oacc[dblk][nq] = MFMA16(va[dblk], pb.b, Oacc[dblk][nq]);
            }
        }
    }

    // cross-wave (key-half) combine + epilogue
    __syncthreads();
    float* Obuf = (float*)smem;                 // [2][16][64] f32x4 = 32 KB
    float* lred = (float*)(smem + 32768);       // [2][4][64]
    if (wk == 1) {
#pragma unroll
        for (int dblk = 0; dblk < 4; ++dblk)
#pragma unroll
            for (int nq = 0; nq < 4; ++nq)
                *(f32x4*)(Obuf + ((wq * 16 + dblk * 4 + nq) * 64 + lane) * 4) = Oacc[dblk][nq];
#pragma unroll
        for (int nq = 0; nq < 4; ++nq)
            lred[(wq * 4 + nq) * 64 + lane] = lacc[nq][0];
    }
    __syncthreads();
    if (wk == 0) {
        float rinv[4];
#pragma unroll
        for (int nq = 0; nq < 4; ++nq)
            rinv[nq] = 1.f / (lacc[nq][0] + lred[(wq * 4 + nq) * 64 + lane]);
        u16* obase = attnO + (size_t)b * S_LEN * D_DIM + h * DHEAD;
#pragma unroll
        for (int dblk = 0; dblk < 4; ++dblk)
#pragma unroll
            for (int nq = 0; nq < 4; ++nq) {
                f32x4 o = Oacc[dblk][nq] + *(const f32x4*)(Obuf + ((wq * 16 + dblk * 4 + nq) * 64 + lane) * 4);
                int q = qt * 128 + wq * 64 + nq * 16 + col16;
                u16x4 pkk;
#pragma unroll
                for (int rr = 0; rr < 4; ++rr) pkk[rr] = f2bf(o[rr] * rinv[nq]);
                *(u16x4*)(obase + (size_t)q * D_DIM + dblk * 16 + quad * 4) = pkk;
            }
    }
}

// ---------------------------------------------------------------------------
// Output GEMM, 128x128 tile, 512 threads, grid (32,8):
// out[s,o] = x[s,o] + bout[o] + attnO·W2^T
__global__ __launch_bounds__(512, 4) void k_oproj(
    const u16* __restrict__ attnO, const u16* __restrict__ W2,
    const float* __restrict__ x, const float* __restrict__ bout, float* __restrict__ out) {
    __shared__ __align__(16) char smem[36864];
    u16* Al = (u16*)smem;              // [128][72]
    u16* Bl = (u16*)(smem + 18432);    // [128][72]
    const int tid = threadIdx.x, lane = tid & 63, w = tid >> 6;
    const int wm = w & 1, wn = w >> 1;
    const int col16 = lane & 15, quad = lane >> 4;
    const int bm = blockIdx.x, bn = blockIdx.y;

    f32x4 acc[4][2];
    const f32x4 z4 = {0.f, 0.f, 0.f, 0.f};
#pragma unroll
    for (int i = 0; i < 4; ++i)
#pragma unroll
        for (int j = 0; j < 2; ++j) acc[i][j] = z4;

    const int ar = tid >> 2, as = tid & 3;
    const u16* pa = attnO + (size_t)(bm * 128 + ar) * D_DIM + as * 16;
    const u16* pb = W2 + (size_t)(bn * 128 + ar) * D_DIM + as * 16;

    u16x8 ra[2], rb[2];
#pragma unroll
    for (int i = 0; i < 2; ++i) ra[i] = *(const u16x8*)(pa + i * 8);
#pragma unroll
    for (int i = 0; i < 2; ++i) rb[i] = *(const u16x8*)(pb + i * 8);

    for (int k0 = 0; k0 < D_DIM; k0 += 64) {
        __syncthreads();
#pragma unroll
        for (int i = 0; i < 2; ++i) *(u16x8*)&Al[ar * 72 + as * 16 + i * 8] = ra[i];
#pragma unroll
        for (int i = 0; i < 2; ++i) *(u16x8*)&Bl[ar * 72 + as * 16 + i * 8] = rb[i];
        __syncthreads();
        if (k0 + 64 < D_DIM) {
#pragma unroll
            for (int i = 0; i < 2; ++i) ra[i] = *(const u16x8*)(pa + k0 + 64 + i * 8);
#pragma unroll
            for (int i = 0; i < 2; ++i) rb[i] = *(const u16x8*)(pb + k0 + 64 + i * 8);
        }
#pragma unroll
        for (int kh = 0; kh < 2; ++kh) {
            bf16x8 af[4];
#pragma unroll
            for (int mt = 0; mt < 4; ++mt)
                af[mt] = *(const bf16x8*)&Al[(wm * 64 + mt * 16 + col16) * 72 + kh * 32 + quad * 8];
#pragma unroll
            for (int nt = 0; nt < 2; ++nt) {
                bf16x8 bfr = *(const bf16x8*)&Bl[(wn * 32 + nt * 16 + col16) * 72 + kh * 32 + quad * 8];
#pragma unroll
                for (int mt = 0; mt < 4; ++mt)
                    acc[mt][nt] = MFMA16(af[mt], bfr, acc[mt][nt]);
            }
        }
    }
#pragma unroll
    for (int nt = 0; nt < 2; ++nt) {
        int col = bn * 128 + wn * 32 + nt * 16 + col16;
        float bv = bout[col];
#pragma unroll
        for (int mt = 0; mt < 4; ++mt) {
            int row0 = bm * 128 + wm * 64 + mt * 16 + quad * 4;
#pragma unroll
            for (int rr = 0; rr < 4; ++rr) {
                size_t idx = (size_t)(row0 + rr) * D_DIM + col;
                out[idx] = acc[mt][nt][rr] + x[idx] + bv;
            }
        }
    }
}

// ---------------------------------------------------------------------------
extern "C" void kernel_launch(void* const* d_in, const int* in_sizes, int n_in,
                              void* d_out, int out_size, void* d_ws, size_t ws_size,
                              hipStream_t stream) {
    const float* x    = (const float*)d_in[0];
    const float* Wq   = (const float*)d_in[1];
    const float* bq   = (const float*)d_in[2];
    const float* Wv   = (const float*)d_in[3];
    const float* Wout = (const float*)d_in[4];
    const float* bout = (const float*)d_in[5];
    const int*   mask = (const int*)d_in[6];
    float* out = (float*)d_out;

    char* ws = (char*)d_ws;
    u16*   Qbf   = (u16*)(ws);                         // 8 MB
    u16*   QT    = (u16*)(ws + (8u << 20));            // 8 MB
    u16*   attnO = (u16*)(ws + (16u << 20));           // 8 MB
    u16*   W2    = (u16*)(ws + (24u << 20));           // 2 MB
    float* Mpart = (float*)(ws + (26u << 20));         // 2 MB (8 partials)
    float* sq05  = (float*)(ws + (28u << 20));         // 256 KB

    k_mega1<<<dim3(384), dim3(512), 0, stream>>>(x, Wq, Wv, bq, mask, Qbf, QT, sq05, Mpart);
    k_mega2<<<dim3(768), dim3(256), 0, stream>>>(Qbf, QT, sq05, attnO, Mpart, Wout, W2);
    k_oproj<<<dim3(32, 8), dim3(512), 0, stream>>>(attnO, W2, x, bout, out);
}